// Round 1
// 660.808 us; speedup vs baseline: 1.0161x; 1.0161x over previous
//
#include <hip/hip_runtime.h>

typedef _Float16 half8   __attribute__((ext_vector_type(8)));
typedef float    floatx4 __attribute__((ext_vector_type(4)));
typedef unsigned int uint4v __attribute__((ext_vector_type(4)));

#define HW      128
#define CIN     256
#define NCHUNK  8
#define HALO_W  24      // 16 + 2*4
#define HALO_H  16      // 8 + 2*4
#define NPIX    (HALO_W * HALO_H)   // 384
#define PITCH   20      // u32 per pixel: 16 data u32 (32 ci halfs) + 4 pad

// Binarize weights -> f16 (+1/-1), pre-permuted to exact MFMA lane order:
// wp[((((b*8 + chunk)*5 + t)*4 + m)*64 + lane)*8 + j]
//   = sign(w_b[co = m*16 + (lane&15)][ci = chunk*32 + (lane>>4)*8 + j][t])
// so each A-fragment load is one fully-coalesced 1KB dwordx4 per wave.
__global__ void prep_weights(const float* __restrict__ w1,
                             const float* __restrict__ w2,
                             const float* __restrict__ w3,
                             const float* __restrict__ w4,
                             _Float16* __restrict__ wp)
{
    int idx  = blockIdx.x * 256 + threadIdx.x;   // 0 .. 327679
    int j    = idx & 7;
    int lane = (idx >> 3) & 63;
    int m    = (idx >> 9) & 3;
    int r3   = idx >> 11;          // 0..159 = t + 5*(chunk + 8*b)
    int t    = r3 % 5;
    int r4   = r3 / 5;             // chunk + 8*b
    int chunk= r4 & 7;
    int b    = r4 >> 3;
    const float* w = (b == 0) ? w1 : (b == 1) ? w2 : (b == 2) ? w3 : w4;
    int co = m * 16 + (lane & 15);
    int ci = chunk * 32 + (lane >> 4) * 8 + j;
    float v = w[(co * 256 + ci) * 5 + t];
    wp[idx] = (v < 0.0f) ? (_Float16)(-1.0f) : (_Float16)(1.0f);
}

// One WG per (16w x 8h) tile per image. 4 waves = 4 branches.
// Wave computes 64 co x 128 pix via mfma_f32_16x16x32_f16.
// LDS double-buffered; staging is pixel-major per thread:
//   one thread = one halo pixel x 8 ci -> 8 coalesced scalar loads,
//   pack to 4 u32, ONE ds_write_b128 at pix*20 + cb*4.
//   Consecutive lanes -> consecutive pixels -> bank starts 20*pix mod 32
//   cover all 32 banks (old layout put 64 lanes on ~2 banks = 32-way conflict).
__global__ __launch_bounds__(256, 2)
void bconv_mfma(const float* __restrict__ x,
                const _Float16* __restrict__ wp,
                const float* __restrict__ bb1,
                const float* __restrict__ bb2,
                const float* __restrict__ bb3,
                const float* __restrict__ bb4,
                float* __restrict__ out)
{
    __shared__ __align__(16) unsigned int xs[2 * NPIX * PITCH]; // 61440 B
    __shared__ float bias_s[256];

    const int tid  = threadIdx.x;
    const int w0t  = blockIdx.x * 16;
    const int h0t  = blockIdx.y * 8;
    const int nimg = blockIdx.z;

    {   // stage all 256 biases (branch-major) into LDS
        int br = tid >> 6, i = tid & 63;
        const float* bp = (br == 0) ? bb1 : (br == 1) ? bb2 : (br == 2) ? bb3 : bb4;
        bias_s[tid] = bp[i];
    }

    const int lane = tid & 63;
    const int wave = tid >> 6;          // branch id: 0=H d1, 1=H d2, 2=V d1, 3=V d2
    const int quad = lane >> 4;
    const int wl   = lane & 15;
    const int dil  = (wave & 1) + 1;
    const bool horiz = (wave < 2);

    floatx4 acc[4][8];
    #pragma unroll
    for (int m = 0; m < 4; ++m)
        #pragma unroll
        for (int n = 0; n < 8; ++n)
            acc[m][n] = (floatx4){0.f, 0.f, 0.f, 0.f};

    // ---- staging: 1536 (pixel, ci-block) tasks, 6 per thread ----
    auto stage = [&](int buf, int chunk) {
        unsigned int* xb = &xs[buf * (NPIX * PITCH)];
        #pragma unroll
        for (int s = 0; s < 6; ++s) {
            int idx = s * 256 + tid;        // 0..1535
            int hh  = idx / 96;             // halo row 0..15
            int rem = idx - hh * 96;
            int cb  = rem / 24;             // ci block of 8: 0..3
            int ww  = rem - cb * 24;        // halo col 0..23
            int hg  = h0t - 4 + hh;
            int wg  = w0t - 4 + ww;
            float v[8];
            #pragma unroll
            for (int jj = 0; jj < 8; ++jj) v[jj] = 0.0f;
            if (hg >= 0 && hg < HW && wg >= 0 && wg < HW) {
                const float* p = x + (((nimg * CIN + chunk * 32 + cb * 8) * HW + hg) * HW + wg);
                #pragma unroll
                for (int jj = 0; jj < 8; ++jj) v[jj] = p[jj * HW * HW];
            }
            uint4v u;
            #pragma unroll
            for (int jj = 0; jj < 4; ++jj)
                u[jj] = __builtin_bit_cast(unsigned int,
                            __builtin_amdgcn_cvt_pkrtz(v[2 * jj], v[2 * jj + 1]));
            // bytes = pix*80 + cb*16 -> 16B aligned b128 write, banks fully spread
            *(uint4v*)&xb[(hh * HALO_W + ww) * PITCH + cb * 4] = u;
        }
    };

    stage(0, 0);

    for (int k = 0; k < NCHUNK; ++k) {
        __syncthreads();   // stage(k) writes visible; all compute(k-1) reads done
        const unsigned int* xb  = &xs[(k & 1) * (NPIX * PITCH)];
        const _Float16*     wpc = wp + (wave * 8 + k) * (5 * 4 * 64 * 8);

        #pragma unroll
        for (int t = 0; t < 5; ++t) {
            half8 B[8];
            #pragma unroll
            for (int n = 0; n < 8; ++n) {
                int hh, ww;
                if (horiz) { hh = n + 4;                  ww = wl + 4 + (t - 2) * dil; }
                else       { hh = n + 4 + (t - 2) * dil;  ww = wl + 4; }
                B[n] = *(const half8*)&xb[(hh * HALO_W + ww) * PITCH + quad * 4];
            }
            #pragma unroll
            for (int m = 0; m < 4; ++m) {
                half8 A = *(const half8*)(wpc + ((t * 4 + m) * 64 + lane) * 8);
                #pragma unroll
                for (int n = 0; n < 8; ++n)
                    acc[m][n] = __builtin_amdgcn_mfma_f32_16x16x32_f16(A, B[n], acc[m][n], 0, 0, 0);
            }
        }

        // prefetch next chunk into the other buffer; next barrier protects it
        if (k + 1 < NCHUNK) stage((k + 1) & 1, k + 1);
    }

    // ---- epilogue: bias + store (D: col=lane&15 -> w, row=quad*4+r -> co) ----
    float bv[4][4];
    #pragma unroll
    for (int m = 0; m < 4; ++m)
        #pragma unroll
        for (int r = 0; r < 4; ++r)
            bv[m][r] = bias_s[wave * 64 + m * 16 + quad * 4 + r];

    #pragma unroll
    for (int m = 0; m < 4; ++m) {
        #pragma unroll
        for (int n = 0; n < 8; ++n) {
            int co   = wave * 64 + m * 16 + quad * 4;
            int base = ((nimg * 256 + co) * HW + (h0t + n)) * HW + w0t + wl;
            #pragma unroll
            for (int r = 0; r < 4; ++r)
                out[base + r * HW * HW] = acc[m][n][r] + bv[m][r];
        }
    }
}

extern "C" void kernel_launch(void* const* d_in, const int* in_sizes, int n_in,
                              void* d_out, int out_size, void* d_ws, size_t ws_size,
                              hipStream_t stream)
{
    (void)in_sizes; (void)n_in; (void)out_size; (void)ws_size;
    const float* x  = (const float*)d_in[0];
    const float* w1 = (const float*)d_in[1];
    const float* b1 = (const float*)d_in[2];
    const float* w2 = (const float*)d_in[3];
    const float* b2 = (const float*)d_in[4];
    const float* w3 = (const float*)d_in[5];
    const float* b3 = (const float*)d_in[6];
    const float* w4 = (const float*)d_in[7];
    const float* b4 = (const float*)d_in[8];
    float*    out = (float*)d_out;
    _Float16* wp  = (_Float16*)d_ws;   // 655360 B

    prep_weights<<<1280, 256, 0, stream>>>(w1, w2, w3, w4, wp);

    dim3 grid(128 / 16, 128 / 8, 16);
    bconv_mfma<<<grid, dim3(256), 0, stream>>>(x, wp, b1, b2, b3, b4, out);
}